// Round 1
// baseline (184.158 us; speedup 1.0000x reference)
//
#include <hip/hip_runtime.h>
#include <hip/hip_bf16.h>

// MessagePassing: out[t] += x[s] for each edge (t, s), D=64.
// edge_index: [2, E] int32 (row 0 = targets, row 1 = sources), x: [N, 64] f32.

#define D 64

__global__ void mp_scatter_add_kernel(const int* __restrict__ tgt,
                                      const int* __restrict__ src,
                                      const float* __restrict__ x,
                                      float* __restrict__ out,
                                      int E) {
    long long tid = (long long)blockIdx.x * blockDim.x + threadIdx.x;
    int e = (int)(tid >> 6);       // edge index
    int d = (int)(tid & 63);       // feature dim
    if (e >= E) return;
    int s = src[e];
    int t = tgt[e];
    atomicAdd(&out[(long long)t * D + d], x[(long long)s * D + d]);
}

extern "C" void kernel_launch(void* const* d_in, const int* in_sizes, int n_in,
                              void* d_out, int out_size, void* d_ws, size_t ws_size,
                              hipStream_t stream) {
    const int* edge_index = (const int*)d_in[0];   // [2, E]
    const float* x        = (const float*)d_in[1]; // [N, 64]
    float* out            = (float*)d_out;         // [N, 64]

    int E = in_sizes[0] / 2;
    const int* tgt = edge_index;       // edge_index[0]
    const int* src = edge_index + E;   // edge_index[1]

    // Harness poisons d_out once and never re-poisons between replays:
    // we must zero it ourselves, every call.
    hipMemsetAsync(d_out, 0, (size_t)out_size * sizeof(float), stream);

    long long total = (long long)E * D;
    int block = 256;
    long long grid = (total + block - 1) / block;
    mp_scatter_add_kernel<<<(dim3)(unsigned)grid, block, 0, stream>>>(tgt, src, x, out, E);
}